// Round 6
// baseline (611.865 us; speedup 1.0000x reference)
//
#include <hip/hip_runtime.h>

#define NN 100000
#define NE 1600000
#define HD 128
#define NL 3
#define NC 40

#define NBK 196     // dst buckets (512 nodes each; 196*512 = 100352 >= NN)
#define NPB 512     // nodes per bucket
#define BSH 9       // bucket shift (dst >> 9)
#define CAP 9216    // per-bucket raw edge capacity (mean 8163, +11 sigma)
#define PCAP 13312  // per-bucket padded CSR capacity: 512*8 + CAP = 13312 exact worst case
#define EPB 2000    // edges per bin block
#define NBINBLK 800 // 800 * 2000 = NE

typedef unsigned int u32;
typedef unsigned short u16;
typedef __attribute__((ext_vector_type(8))) short short8;
typedef __attribute__((ext_vector_type(4))) float f32x4;

__device__ __forceinline__ float b2f(u16 h){
    union{u32 u; float f;} v; v.u = ((u32)h) << 16; return v.f;
}
__device__ __forceinline__ u16 f2b(float f){
    union{float f; u32 u;} v; v.f = f;
    u32 u = v.u;
    u32 r = (u + 0x7FFFu + ((u >> 16) & 1u)) >> 16;
    return (u16)r;
}

// ---------------- weight conversion ----------------
// Wt[l][n][k] = W[l][k][n]  (transposed, bf16)
__global__ void k_conv_w(const float* __restrict__ Ws, u16* __restrict__ wt){
    int i = blockIdx.x * blockDim.x + threadIdx.x;
    if (i >= NL * HD * HD) return;
    int l = i / (HD * HD);
    int r = i % (HD * HD);
    int n = r / HD;
    int k = r % HD;
    wt[i] = f2b(Ws[l * HD * HD + k * HD + n]);
}

// ---------------- x -> bf16 + first head pass: out = b_out + x @ W_out[0:128] ----------------
__launch_bounds__(256)
__global__ void k_convhead(const float* __restrict__ x, const float* __restrict__ wout,
                           const float* __restrict__ bout, float* __restrict__ out,
                           u16* __restrict__ hA){
    __shared__ float wl[HD * NC]; // rows 0..127 of W_out
    __shared__ float bl[NC];
    int tid = threadIdx.x;
    for (int i = tid; i < HD * NC; i += 256) wl[i] = wout[i];
    if (tid < NC) bl[tid] = bout[tid];
    __syncthreads();
    int n = blockIdx.x * 256 + tid;
    if (n >= NN) return;
    f32x4 acc[10];
    #pragma unroll
    for (int q = 0; q < 10; q++) acc[q] = *reinterpret_cast<const f32x4*>(&bl[q * 4]);
    const float* xr = x + (size_t)n * HD;
    #pragma unroll
    for (int k8 = 0; k8 < HD / 8; k8++){
        float4 v0 = reinterpret_cast<const float4*>(xr)[k8 * 2];
        float4 v1 = reinterpret_cast<const float4*>(xr)[k8 * 2 + 1];
        float xs[8] = {v0.x, v0.y, v0.z, v0.w, v1.x, v1.y, v1.z, v1.w};
        uint4 ov;
        u16* po = (u16*)&ov;
        #pragma unroll
        for (int t = 0; t < 8; t++){
            int f = k8 * 8 + t;
            po[t] = f2b(xs[t]);
            const f32x4* wr = reinterpret_cast<const f32x4*>(&wl[f * NC]);
            #pragma unroll
            for (int q = 0; q < 10; q++) acc[q] += xs[t] * wr[q];
        }
        reinterpret_cast<uint4*>(hA + (size_t)n * HD)[k8] = ov;
    }
    float* orw = out + (size_t)n * NC;
    #pragma unroll
    for (int q = 0; q < 10; q++) reinterpret_cast<f32x4*>(orw)[q] = acc[q];
}

// ---------------- pass 1: bin edges by dst bucket, coalesced grouped writes ----------------
__launch_bounds__(256)
__global__ void k_bin(const int* __restrict__ src, const int* __restrict__ dst,
                      int* __restrict__ gcur, uint2* __restrict__ bb){
    __shared__ int hist[NBK];
    __shared__ int lbase[NBK];
    __shared__ int gbase[NBK];
    __shared__ int cur[NBK];
    __shared__ uint2 stage[EPB]; // 16 KB
    int tid = threadIdx.x;
    int e0 = blockIdx.x * EPB;
    for (int i = tid; i < NBK; i += 256) hist[i] = 0;
    __syncthreads();
    for (int k = tid; k < EPB; k += 256){
        int d = dst[e0 + k];
        atomicAdd(&hist[d >> BSH], 1);
    }
    __syncthreads();
    if (tid == 0){
        int run = 0;
        for (int b = 0; b < NBK; b++){ lbase[b] = run; cur[b] = run; run += hist[b]; }
    }
    __syncthreads();
    if (tid < NBK) gbase[tid] = atomicAdd(&gcur[tid], hist[tid]);
    __syncthreads();
    for (int k = tid; k < EPB; k += 256){
        int s = src[e0 + k], d = dst[e0 + k];
        int pos = atomicAdd(&cur[d >> BSH], 1);
        stage[pos] = make_uint2((u32)s, (u32)d);
    }
    __syncthreads();
    for (int k = tid; k < EPB; k += 256){
        uint2 sd = stage[k];
        int b = (int)(sd.y >> BSH);
        int g = gbase[b] + (k - lbase[b]);
        if (g < CAP) bb[(size_t)b * CAP + g] = sd;
    }
}

// ---------------- pass 2: per-bucket padded CSR build, all global I/O coalesced ----------------
// Per node layout: [self, neighbors..., pad(NN)...] length rounded up to multiple of 8.
// offs[n] = start, oend[n] = start + padded-length (true per-node end; avoids bucket-gap).
__launch_bounds__(512)
__global__ void k_csr(const int* __restrict__ gcur, const uint2* __restrict__ bb,
                      int* __restrict__ csr_src, int* __restrict__ offs,
                      int* __restrict__ oend, float* __restrict__ dinv){
    __shared__ int hist[NPB];
    __shared__ int cur[NPB];
    __shared__ int wsum[8];
    __shared__ int totp_s;
    __shared__ int lcsr[PCAP]; // 52 KB
    int tid = threadIdx.x;
    int b = blockIdx.x;
    int cnt_b = gcur[b]; if (cnt_b > CAP) cnt_b = CAP;
    const uint2* eb = bb + (size_t)b * CAP;
    hist[tid] = 0;
    __syncthreads();
    for (int k = tid; k < cnt_b; k += 512)
        atomicAdd(&hist[eb[k].y & (NPB - 1)], 1);
    __syncthreads();
    int cnt = hist[tid];
    int ps = (1 + cnt + 7) & ~7;   // padded slots incl self
    int lane = tid & 63, w = tid >> 6;
    int incl = ps;
    #pragma unroll
    for (int dlt = 1; dlt < 64; dlt <<= 1){
        int t = __shfl_up(incl, dlt);
        if (lane >= dlt) incl += t;
    }
    if (lane == 63) wsum[w] = incl;
    __syncthreads();
    if (tid == 0){
        int run = 0;
        #pragma unroll
        for (int j = 0; j < 8; j++){ int t = wsum[j]; wsum[j] = run; run += t; }
        totp_s = run;
    }
    __syncthreads();
    int excl = wsum[w] + incl - ps;
    int n = b * NPB + tid;
    offs[n] = b * PCAP + excl;
    oend[n] = b * PCAP + excl + ps;
    if (n < NN) dinv[n] = rsqrtf((float)(cnt + 1));
    cur[tid] = excl + 1;           // neighbors start after self slot
    int totp = totp_s;
    __syncthreads();
    for (int k = tid; k < totp; k += 512) lcsr[k] = NN;   // pad -> zero row
    __syncthreads();
    lcsr[excl] = (n < NN) ? n : NN;    // self edge (tail nodes -> zero row)
    __syncthreads();
    for (int k = tid; k < cnt_b; k += 512){
        uint2 sd = eb[k];
        int pos = atomicAdd(&cur[sd.y & (NPB - 1)], 1);
        lcsr[pos] = (int)sd.x;
    }
    __syncthreads();
    for (int k = tid; k < totp; k += 512)
        csr_src[b * PCAP + k] = lcsr[k];
}

// ---------------- dense GEMM: hw = (h @ W) * dinv[row]  (MFMA bf16) ----------------
__launch_bounds__(256)
__global__ void k_gemm(const u16* __restrict__ h, const u16* __restrict__ wt,
                       const float* __restrict__ dinv, u16* __restrict__ out){
    __shared__ u16 wlds[HD * HD]; // 32KB, XOR-swizzled in 16B units
    int tid = threadIdx.x;
    {
        const uint4* g = reinterpret_cast<const uint4*>(wt);
        #pragma unroll
        for (int i = 0; i < 8; i++){
            int lin16 = tid + 256 * i;
            uint4 v = g[lin16];
            int c = lin16 >> 4;
            int addr16 = lin16 ^ (c & 7);
            reinterpret_cast<uint4*>(wlds)[addr16] = v;
        }
    }
    __syncthreads();

    int wv = tid >> 6, lane = tid & 63;
    int row_base = blockIdx.x * 64 + wv * 16;
    int arow = row_base + (lane & 15);
    if (arow >= NN) arow = NN - 1;
    int koff = (lane >> 4) * 8;

    f32x4 acc[8];
    #pragma unroll
    for (int t = 0; t < 8; t++) acc[t] = (f32x4){0.f, 0.f, 0.f, 0.f};

    #pragma unroll
    for (int kk = 0; kk < 4; kk++){
        short8 a = *reinterpret_cast<const short8*>(h + arow * HD + kk * 32 + koff);
        #pragma unroll
        for (int ct = 0; ct < 8; ct++){
            int c = ct * 16 + (lane & 15);
            int addr16 = (c * 16 + kk * 4 + (koff >> 3)) ^ (c & 7);
            short8 b = *reinterpret_cast<const short8*>(wlds + addr16 * 8);
            acc[ct] = __builtin_amdgcn_mfma_f32_16x16x32_bf16(a, b, acc[ct], 0, 0, 0);
        }
    }

    int drow = row_base + (lane >> 4) * 4;
    int dcol = lane & 15;
    float dv[4];
    #pragma unroll
    for (int r = 0; r < 4; r++){
        int rr = drow + r;
        dv[r] = dinv[rr < NN ? rr : NN - 1];
    }
    #pragma unroll
    for (int ct = 0; ct < 8; ct++){
        #pragma unroll
        for (int r = 0; r < 4; r++){
            int rr = drow + r;
            if (rr < NN) out[rr * HD + ct * 16 + dcol] = f2b(acc[ct][r] * dv[r]);
        }
    }
}

// ---------------- aggregation + BN stats ----------------
// wave per 8 contiguous nodes; padded CSR (self + pad included, multiple of 8)
// All 8 nodes' metadata + index vectors prefetched upfront -> per-node chain is gather-only.
__launch_bounds__(256)
__global__ void k_agg(const u16* __restrict__ hw, const int* __restrict__ offs,
                      const int* __restrict__ oend, const int* __restrict__ csr_src,
                      const float* __restrict__ dinv, const float* __restrict__ bias,
                      u16* __restrict__ agg, float* __restrict__ sums){
    __shared__ float redS[4][HD];
    __shared__ float redQ[4][HD];
    int tid = threadIdx.x;
    int lane = tid & 63;
    int wv = tid >> 6;
    int f0 = lane * 2;
    float b0 = bias[f0], b1 = bias[f0 + 1];
    float s0 = 0.f, s1 = 0.f, q0 = 0.f, q1 = 0.f;
    int n0 = (blockIdx.x * 4 + wv) * 8;
    const u32* hw32 = reinterpret_cast<const u32*>(hw); // row = 64 u32, lane offset = lane

    // batch metadata: offs/oend for the wave's 8 nodes (one 32B txn each)
    int mvo = offs[n0 + (lane & 7)];
    int mve = oend[n0 + (lane & 7)];

    // prefetch all 8 index vectors upfront (independent coalesced loads)
    int idxs[8];
    #pragma unroll
    for (int k = 0; k < 8; k++){
        int ek = __builtin_amdgcn_readlane(mvo, k);
        idxs[k] = csr_src[ek + lane];
    }

    #pragma unroll
    for (int k = 0; k < 8; k++){
        int n = n0 + k;
        if (n < NN){
            int e  = __builtin_amdgcn_readlane(mvo, k);
            int we = __builtin_amdgcn_readlane(mve, k) - e;   // padded len, mult of 8, >=8
            int idxv = idxs[k];
            float a0 = 0.f, a1 = 0.f, c0 = 0.f, c1 = 0.f;
            int win = we < 64 ? we : 64;
            int nch = win >> 3;
            u32 va[8], vb[8];
            #pragma unroll
            for (int j = 0; j < 8; j++){
                u32 uid = (u32)__builtin_amdgcn_readlane(idxv, j);
                va[j] = hw32[(size_t)(uid << 6) + (u32)lane];
            }
            for (int c = 1; c < nch; c++){
                if (c & 1){
                    #pragma unroll
                    for (int j = 0; j < 8; j++){
                        u32 uid = (u32)__builtin_amdgcn_readlane(idxv, c * 8 + j);
                        vb[j] = hw32[(size_t)(uid << 6) + (u32)lane];
                    }
                    #pragma unroll
                    for (int j = 0; j < 8; j++){
                        union{u32 u; float f;} L, H;
                        L.u = va[j] << 16; H.u = va[j] & 0xFFFF0000u;
                        a0 += L.f; a1 += H.f;
                    }
                } else {
                    #pragma unroll
                    for (int j = 0; j < 8; j++){
                        u32 uid = (u32)__builtin_amdgcn_readlane(idxv, c * 8 + j);
                        va[j] = hw32[(size_t)(uid << 6) + (u32)lane];
                    }
                    #pragma unroll
                    for (int j = 0; j < 8; j++){
                        union{u32 u; float f;} L, H;
                        L.u = vb[j] << 16; H.u = vb[j] & 0xFFFF0000u;
                        c0 += L.f; c1 += H.f;
                    }
                }
            }
            if (nch & 1){
                #pragma unroll
                for (int j = 0; j < 8; j++){
                    union{u32 u; float f;} L, H;
                    L.u = va[j] << 16; H.u = va[j] & 0xFFFF0000u;
                    a0 += L.f; a1 += H.f;
                }
            } else {
                #pragma unroll
                for (int j = 0; j < 8; j++){
                    union{u32 u; float f;} L, H;
                    L.u = vb[j] << 16; H.u = vb[j] & 0xFFFF0000u;
                    c0 += L.f; c1 += H.f;
                }
            }
            // rare tail: padded degree > 64 (Poisson(16) makes this ~never)
            int rem = we - win;
            int ee = e + win;
            while (rem > 0){
                int win2 = rem < 64 ? rem : 64;
                int iv = csr_src[ee + lane];
                int nc2 = win2 >> 3;
                for (int c = 0; c < nc2; c++){
                    u32 vx[8];
                    #pragma unroll
                    for (int j = 0; j < 8; j++){
                        u32 uid = (u32)__builtin_amdgcn_readlane(iv, c * 8 + j);
                        vx[j] = hw32[(size_t)(uid << 6) + (u32)lane];
                    }
                    #pragma unroll
                    for (int j = 0; j < 8; j++){
                        union{u32 u; float f;} L, H;
                        L.u = vx[j] << 16; H.u = vx[j] & 0xFFFF0000u;
                        a0 += L.f; a1 += H.f;
                    }
                }
                ee += win2; rem -= win2;
            }
            float di = dinv[n];
            a0 = (a0 + c0) * di + b0;
            a1 = (a1 + c1) * di + b1;
            u32 o = ((u32)f2b(a1) << 16) | (u32)f2b(a0);
            *reinterpret_cast<u32*>(agg + (size_t)n * HD + f0) = o;
            s0 += a0; s1 += a1; q0 += a0 * a0; q1 += a1 * a1;
        }
    }

    redS[wv][f0] = s0; redS[wv][f0 + 1] = s1;
    redQ[wv][f0] = q0; redQ[wv][f0 + 1] = q1;
    __syncthreads();
    if (tid < HD){
        float ts = redS[0][tid] + redS[1][tid] + redS[2][tid] + redS[3][tid];
        float tq = redQ[0][tid] + redQ[1][tid] + redQ[2][tid] + redQ[3][tid];
        atomicAdd(&sums[tid], ts);
        atomicAdd(&sums[HD + tid], tq);
    }
}

__global__ void k_bnprep(const float* __restrict__ sums, const float* __restrict__ gamma,
                         const float* __restrict__ beta, float* __restrict__ bn){
    int f = threadIdx.x;
    if (f >= HD) return;
    float mu = sums[f] / (float)NN;
    float var = sums[HD + f] / (float)NN - mu * mu;
    float inv = rsqrtf(var + 1e-5f);
    float a = gamma[f] * inv;
    bn[f] = a;
    bn[HD + f] = beta[f] - mu * a;
}

// ---------------- fused BN-apply + head: hA = BN(agg); out += hA @ W_out[row0:row0+128] ----------------
__launch_bounds__(256)
__global__ void k_bnhead(const u16* __restrict__ agg, const float* __restrict__ bn,
                         const float* __restrict__ wout, float* __restrict__ out,
                         u16* __restrict__ hA, int row0){
    __shared__ float wl[HD * NC]; // 20KB
    __shared__ float A[HD];
    __shared__ float C[HD];
    int tid = threadIdx.x;
    for (int i = tid; i < HD * NC; i += 256) wl[i] = wout[row0 * NC + i];
    if (tid < HD){ A[tid] = bn[tid]; C[tid] = bn[HD + tid]; }
    __syncthreads();
    int n = blockIdx.x * 256 + tid;
    if (n >= NN) return;
    float* orw = out + (size_t)n * NC;
    f32x4 acc[10];
    #pragma unroll
    for (int q = 0; q < 10; q++) acc[q] = reinterpret_cast<const f32x4*>(orw)[q];
    #pragma unroll
    for (int k8 = 0; k8 < HD / 8; k8++){
        uint4 v = reinterpret_cast<const uint4*>(agg + (size_t)n * HD)[k8];
        const u16* pv = (const u16*)&v;
        uint4 ov;
        u16* po = (u16*)&ov;
        #pragma unroll
        for (int t = 0; t < 8; t++){
            int f = k8 * 8 + t;
            float xv = b2f(pv[t]) * A[f] + C[f];
            po[t] = f2b(xv);
            const f32x4* wr = reinterpret_cast<const f32x4*>(&wl[f * NC]);
            #pragma unroll
            for (int q = 0; q < 10; q++) acc[q] += xv * wr[q];
        }
        reinterpret_cast<uint4*>(hA + (size_t)n * HD)[k8] = ov;
    }
    #pragma unroll
    for (int q = 0; q < 10; q++) reinterpret_cast<f32x4*>(orw)[q] = acc[q];
}

// ---------------- launch ----------------
extern "C" void kernel_launch(void* const* d_in, const int* in_sizes, int n_in,
                              void* d_out, int out_size, void* d_ws, size_t ws_size,
                              hipStream_t stream){
    const float* x      = (const float*)d_in[0];
    const float* Ws     = (const float*)d_in[1];
    const float* bs     = (const float*)d_in[2];
    const float* gammas = (const float*)d_in[3];
    const float* betas  = (const float*)d_in[4];
    const float* W_out  = (const float*)d_in[5];
    const float* b_out  = (const float*)d_in[6];
    const int*   ei     = (const int*)d_in[7];
    const int* src = ei;
    const int* dst = ei + NE;
    float* out = (float*)d_out;

    char* ws = (char*)d_ws;
    size_t off = 0;
    auto alloc = [&](size_t bytes) -> char* {
        char* p = ws + off;
        off += (bytes + 255) & ~(size_t)255;
        return p;
    };
    u16*   hA       = (u16*)alloc((size_t)NN * HD * 2);
    u16*   hw       = (u16*)alloc((size_t)(NN + 1) * HD * 2);  // +1 zero row for CSR padding
    u16*   aggb     = (u16*)alloc((size_t)NN * HD * 2);        // aliased: bucket buffer pre-loop
    u16*   wt       = (u16*)alloc((size_t)NL * HD * HD * 2);
    float* dinv     = (float*)alloc((size_t)NN * 4);
    int*   offs     = (int*)alloc((size_t)(NBK * NPB) * 4);
    int*   oend     = (int*)alloc((size_t)(NBK * NPB) * 4);
    int*   gcur     = (int*)alloc((size_t)NBK * 4);
    int*   csr_src  = (int*)alloc(((size_t)NBK * PCAP + 256) * 4);
    float* stats    = (float*)alloc((size_t)NL * 2 * HD * 4);
    float* bn       = (float*)alloc((size_t)2 * HD * 4);

    uint2* bb = (uint2*)aggb; // 196*9216*8 = 14.45 MB <= 25.6 MB; dead before layer loop

    hipMemsetAsync(gcur, 0, (size_t)NBK * 4, stream);
    hipMemsetAsync(stats, 0, (size_t)NL * 2 * HD * 4, stream);
    hipMemsetAsync(hw + (size_t)NN * HD, 0, HD * 2, stream);   // zero row NN

    k_conv_w<<<(NL * HD * HD + 255) / 256, 256, 0, stream>>>(Ws, wt);
    k_bin<<<NBINBLK, 256, 0, stream>>>(src, dst, gcur, bb);
    k_csr<<<NBK, 512, 0, stream>>>(gcur, bb, csr_src, offs, oend, dinv);

    k_convhead<<<(NN + 255) / 256, 256, 0, stream>>>(x, W_out, b_out, out, hA);

    for (int l = 0; l < NL; l++){
        k_gemm<<<(NN + 63) / 64, 256, 0, stream>>>(hA, wt + (size_t)l * HD * HD, dinv, hw);
        k_agg<<<NN / 32, 256, 0, stream>>>(hw, offs, oend, csr_src, dinv,
                                           bs + (size_t)l * HD, aggb,
                                           stats + (size_t)l * 2 * HD);
        k_bnprep<<<1, 128, 0, stream>>>(stats + (size_t)l * 2 * HD,
                                        gammas + (size_t)l * HD, betas + (size_t)l * HD, bn);
        k_bnhead<<<(NN + 255) / 256, 256, 0, stream>>>(aggb, bn, W_out, out, hA,
                                                       HD + l * HD);
    }
}

// Round 7
// 566.170 us; speedup vs baseline: 1.0807x; 1.0807x over previous
//
#include <hip/hip_runtime.h>

#define NN 100000
#define NE 1600000
#define HD 128
#define NL 3
#define NC 40

#define NBK 196     // dst buckets (512 nodes each; 196*512 = 100352 >= NN)
#define NPB 512     // nodes per bucket
#define BSH 9       // bucket shift (dst >> 9)
#define CAP 9216    // per-bucket raw edge capacity (mean 8163, +11 sigma)
#define PCAP 13312  // per-bucket padded CSR capacity: 512*8 + CAP = 13312 exact worst case
#define EPB 2000    // edges per bin block
#define NBINBLK 800 // 800 * 2000 = NE

typedef unsigned int u32;
typedef unsigned short u16;
typedef __attribute__((ext_vector_type(8))) short short8;
typedef __attribute__((ext_vector_type(4))) float f32x4;

__device__ __forceinline__ float b2f(u16 h){
    union{u32 u; float f;} v; v.u = ((u32)h) << 16; return v.f;
}
__device__ __forceinline__ u16 f2b(float f){
    union{float f; u32 u;} v; v.f = f;
    u32 u = v.u;
    u32 r = (u + 0x7FFFu + ((u >> 16) & 1u)) >> 16;
    return (u16)r;
}

// ---------------- weight conversion ----------------
// Wt[l][n][k] = W[l][k][n]  (transposed, bf16)
__global__ void k_conv_w(const float* __restrict__ Ws, u16* __restrict__ wt){
    int i = blockIdx.x * blockDim.x + threadIdx.x;
    if (i >= NL * HD * HD) return;
    int l = i / (HD * HD);
    int r = i % (HD * HD);
    int n = r / HD;
    int k = r % HD;
    wt[i] = f2b(Ws[l * HD * HD + k * HD + n]);
}

// ---------------- x -> bf16 + first head pass: out = b_out + x @ W_out[0:128] ----------------
__launch_bounds__(256)
__global__ void k_convhead(const float* __restrict__ x, const float* __restrict__ wout,
                           const float* __restrict__ bout, float* __restrict__ out,
                           u16* __restrict__ hA){
    __shared__ float wl[HD * NC]; // rows 0..127 of W_out
    __shared__ float bl[NC];
    int tid = threadIdx.x;
    for (int i = tid; i < HD * NC; i += 256) wl[i] = wout[i];
    if (tid < NC) bl[tid] = bout[tid];
    __syncthreads();
    int n = blockIdx.x * 256 + tid;
    if (n >= NN) return;
    f32x4 acc[10];
    #pragma unroll
    for (int q = 0; q < 10; q++) acc[q] = *reinterpret_cast<const f32x4*>(&bl[q * 4]);
    const float* xr = x + (size_t)n * HD;
    #pragma unroll
    for (int k8 = 0; k8 < HD / 8; k8++){
        float4 v0 = reinterpret_cast<const float4*>(xr)[k8 * 2];
        float4 v1 = reinterpret_cast<const float4*>(xr)[k8 * 2 + 1];
        float xs[8] = {v0.x, v0.y, v0.z, v0.w, v1.x, v1.y, v1.z, v1.w};
        uint4 ov;
        u16* po = (u16*)&ov;
        #pragma unroll
        for (int t = 0; t < 8; t++){
            int f = k8 * 8 + t;
            po[t] = f2b(xs[t]);
            const f32x4* wr = reinterpret_cast<const f32x4*>(&wl[f * NC]);
            #pragma unroll
            for (int q = 0; q < 10; q++) acc[q] += xs[t] * wr[q];
        }
        reinterpret_cast<uint4*>(hA + (size_t)n * HD)[k8] = ov;
    }
    float* orw = out + (size_t)n * NC;
    #pragma unroll
    for (int q = 0; q < 10; q++) reinterpret_cast<f32x4*>(orw)[q] = acc[q];
}

// ---------------- pass 1: bin edges by dst bucket, coalesced grouped writes ----------------
__launch_bounds__(256)
__global__ void k_bin(const int* __restrict__ src, const int* __restrict__ dst,
                      int* __restrict__ gcur, uint2* __restrict__ bb){
    __shared__ int hist[NBK];
    __shared__ int lbase[NBK];
    __shared__ int gbase[NBK];
    __shared__ int cur[NBK];
    __shared__ uint2 stage[EPB]; // 16 KB
    int tid = threadIdx.x;
    int e0 = blockIdx.x * EPB;
    for (int i = tid; i < NBK; i += 256) hist[i] = 0;
    __syncthreads();
    for (int k = tid; k < EPB; k += 256){
        int d = dst[e0 + k];
        atomicAdd(&hist[d >> BSH], 1);
    }
    __syncthreads();
    if (tid == 0){
        int run = 0;
        for (int b = 0; b < NBK; b++){ lbase[b] = run; cur[b] = run; run += hist[b]; }
    }
    __syncthreads();
    if (tid < NBK) gbase[tid] = atomicAdd(&gcur[tid], hist[tid]);
    __syncthreads();
    for (int k = tid; k < EPB; k += 256){
        int s = src[e0 + k], d = dst[e0 + k];
        int pos = atomicAdd(&cur[d >> BSH], 1);
        stage[pos] = make_uint2((u32)s, (u32)d);
    }
    __syncthreads();
    for (int k = tid; k < EPB; k += 256){
        uint2 sd = stage[k];
        int b = (int)(sd.y >> BSH);
        int g = gbase[b] + (k - lbase[b]);
        if (g < CAP) bb[(size_t)b * CAP + g] = sd;
    }
}

// ---------------- pass 2: per-bucket padded CSR build, all global I/O coalesced ----------------
// Per node layout: [self, neighbors..., pad(NN)...] length rounded up to multiple of 8.
// offs[n] = start, oend[n] = start + padded-length (true per-node end; avoids bucket-gap).
__launch_bounds__(512)
__global__ void k_csr(const int* __restrict__ gcur, const uint2* __restrict__ bb,
                      int* __restrict__ csr_src, int* __restrict__ offs,
                      int* __restrict__ oend, float* __restrict__ dinv){
    __shared__ int hist[NPB];
    __shared__ int cur[NPB];
    __shared__ int wsum[8];
    __shared__ int totp_s;
    __shared__ int lcsr[PCAP]; // 52 KB
    int tid = threadIdx.x;
    int b = blockIdx.x;
    int cnt_b = gcur[b]; if (cnt_b > CAP) cnt_b = CAP;
    const uint2* eb = bb + (size_t)b * CAP;
    hist[tid] = 0;
    __syncthreads();
    for (int k = tid; k < cnt_b; k += 512)
        atomicAdd(&hist[eb[k].y & (NPB - 1)], 1);
    __syncthreads();
    int cnt = hist[tid];
    int ps = (1 + cnt + 7) & ~7;   // padded slots incl self
    int lane = tid & 63, w = tid >> 6;
    int incl = ps;
    #pragma unroll
    for (int dlt = 1; dlt < 64; dlt <<= 1){
        int t = __shfl_up(incl, dlt);
        if (lane >= dlt) incl += t;
    }
    if (lane == 63) wsum[w] = incl;
    __syncthreads();
    if (tid == 0){
        int run = 0;
        #pragma unroll
        for (int j = 0; j < 8; j++){ int t = wsum[j]; wsum[j] = run; run += t; }
        totp_s = run;
    }
    __syncthreads();
    int excl = wsum[w] + incl - ps;
    int n = b * NPB + tid;
    offs[n] = b * PCAP + excl;
    oend[n] = b * PCAP + excl + ps;
    if (n < NN) dinv[n] = rsqrtf((float)(cnt + 1));
    cur[tid] = excl + 1;           // neighbors start after self slot
    int totp = totp_s;
    __syncthreads();
    for (int k = tid; k < totp; k += 512) lcsr[k] = NN;   // pad -> zero row
    __syncthreads();
    lcsr[excl] = (n < NN) ? n : NN;    // self edge (tail nodes -> zero row)
    __syncthreads();
    for (int k = tid; k < cnt_b; k += 512){
        uint2 sd = eb[k];
        int pos = atomicAdd(&cur[sd.y & (NPB - 1)], 1);
        lcsr[pos] = (int)sd.x;
    }
    __syncthreads();
    for (int k = tid; k < totp; k += 512)
        csr_src[b * PCAP + k] = lcsr[k];
}

// ---------------- dense GEMM: hw = (h @ W) * dinv[row]  (MFMA bf16) ----------------
__launch_bounds__(256)
__global__ void k_gemm(const u16* __restrict__ h, const u16* __restrict__ wt,
                       const float* __restrict__ dinv, u16* __restrict__ out){
    __shared__ u16 wlds[HD * HD]; // 32KB, XOR-swizzled in 16B units
    int tid = threadIdx.x;
    {
        const uint4* g = reinterpret_cast<const uint4*>(wt);
        #pragma unroll
        for (int i = 0; i < 8; i++){
            int lin16 = tid + 256 * i;
            uint4 v = g[lin16];
            int c = lin16 >> 4;
            int addr16 = lin16 ^ (c & 7);
            reinterpret_cast<uint4*>(wlds)[addr16] = v;
        }
    }
    __syncthreads();

    int wv = tid >> 6, lane = tid & 63;
    int row_base = blockIdx.x * 64 + wv * 16;
    int arow = row_base + (lane & 15);
    if (arow >= NN) arow = NN - 1;
    int koff = (lane >> 4) * 8;

    f32x4 acc[8];
    #pragma unroll
    for (int t = 0; t < 8; t++) acc[t] = (f32x4){0.f, 0.f, 0.f, 0.f};

    #pragma unroll
    for (int kk = 0; kk < 4; kk++){
        short8 a = *reinterpret_cast<const short8*>(h + arow * HD + kk * 32 + koff);
        #pragma unroll
        for (int ct = 0; ct < 8; ct++){
            int c = ct * 16 + (lane & 15);
            int addr16 = (c * 16 + kk * 4 + (koff >> 3)) ^ (c & 7);
            short8 b = *reinterpret_cast<const short8*>(wlds + addr16 * 8);
            acc[ct] = __builtin_amdgcn_mfma_f32_16x16x32_bf16(a, b, acc[ct], 0, 0, 0);
        }
    }

    int drow = row_base + (lane >> 4) * 4;
    int dcol = lane & 15;
    float dv[4];
    #pragma unroll
    for (int r = 0; r < 4; r++){
        int rr = drow + r;
        dv[r] = dinv[rr < NN ? rr : NN - 1];
    }
    #pragma unroll
    for (int ct = 0; ct < 8; ct++){
        #pragma unroll
        for (int r = 0; r < 4; r++){
            int rr = drow + r;
            if (rr < NN) out[rr * HD + ct * 16 + dcol] = f2b(acc[ct][r] * dv[r]);
        }
    }
}

// ---------------- aggregation + BN stats ----------------
// wave per 16 contiguous nodes, processed PAIRWISE for 2x memory-level parallelism.
// Padded CSR (self + pad to mult of 8). Index vectors software-prefetched one pair ahead.
#define ACC8(buf, x0, x1) { _Pragma("unroll") \
    for (int j = 0; j < 8; j++){ \
        union{u32 u; float f;} L, H; \
        L.u = buf[j] << 16; H.u = buf[j] & 0xFFFF0000u; \
        x0 += L.f; x1 += H.f; } }

#define GATHER8(buf, iv, c) { _Pragma("unroll") \
    for (int j = 0; j < 8; j++){ \
        u32 uid = (u32)__builtin_amdgcn_readlane(iv, (c) * 8 + j); \
        buf[j] = hw32[((size_t)uid << 6) + (u32)lane]; } }

__launch_bounds__(256)
__global__ void k_agg(const u16* __restrict__ hw, const int* __restrict__ offs,
                      const int* __restrict__ oend, const int* __restrict__ csr_src,
                      const float* __restrict__ dinv, const float* __restrict__ bias,
                      u16* __restrict__ agg, float* __restrict__ sums){
    __shared__ float redS[4][HD];
    __shared__ float redQ[4][HD];
    int tid = threadIdx.x;
    int lane = tid & 63;
    int wv = tid >> 6;
    int f0 = lane * 2;
    float b0 = bias[f0], b1 = bias[f0 + 1];
    float s0 = 0.f, s1 = 0.f, q0 = 0.f, q1 = 0.f;
    int n0 = (blockIdx.x * 4 + wv) * 16;
    const u32* hw32 = reinterpret_cast<const u32*>(hw); // row = 64 u32, lane offset = lane

    // batch metadata for the wave's 16 nodes (one coalesced load each)
    int mvo = offs[n0 + (lane & 15)];
    int mve = oend[n0 + (lane & 15)];

    // prefetch first pair's index vectors
    int ivA = csr_src[__builtin_amdgcn_readlane(mvo, 0) + lane];
    int ivB = csr_src[__builtin_amdgcn_readlane(mvo, 1) + lane];

    #pragma unroll 1
    for (int k = 0; k < 16; k += 2){
        int nA = n0 + k, nB = n0 + k + 1;
        int eA = __builtin_amdgcn_readlane(mvo, k);
        int wA = __builtin_amdgcn_readlane(mve, k) - eA;
        int eB = __builtin_amdgcn_readlane(mvo, k + 1);
        int wB = __builtin_amdgcn_readlane(mve, k + 1) - eB;
        int nchA = (wA < 64 ? wA : 64) >> 3;   // >= 1 always (padded len >= 8)
        int nchB = (wB < 64 ? wB : 64) >> 3;
        int nch = nchA > nchB ? nchA : nchB;

        u32 vaA[8], vbA[8], vaB[8], vbB[8];
        float aA0 = 0.f, aA1 = 0.f, cA0 = 0.f, cA1 = 0.f;
        float aB0 = 0.f, aB1 = 0.f, cB0 = 0.f, cB1 = 0.f;

        // round 0: 16 gathers in flight
        GATHER8(vaA, ivA, 0);
        GATHER8(vaB, ivB, 0);

        // prefetch next pair's index vectors ((k+2)&15 wraps harmlessly on last pair)
        int ivA_n = csr_src[__builtin_amdgcn_readlane(mvo, (k + 2) & 15) + lane];
        int ivB_n = csr_src[__builtin_amdgcn_readlane(mvo, (k + 3) & 15) + lane];

        for (int c = 1; c < nch; c++){
            if (c & 1){
                if (c < nchA) GATHER8(vbA, ivA, c);
                if (c < nchB) GATHER8(vbB, ivB, c);
                if (c - 1 < nchA) ACC8(vaA, aA0, aA1);
                if (c - 1 < nchB) ACC8(vaB, aB0, aB1);
            } else {
                if (c < nchA) GATHER8(vaA, ivA, c);
                if (c < nchB) GATHER8(vaB, ivB, c);
                if (c - 1 < nchA) ACC8(vbA, cA0, cA1);
                if (c - 1 < nchB) ACC8(vbB, cB0, cB1);
            }
        }
        // consume final chunk (index nch-1, parity (nch-1)&1) for nodes whose nchX == nch
        if ((nch - 1) & 1){
            if (nchA == nch) ACC8(vbA, cA0, cA1);
            if (nchB == nch) ACC8(vbB, cB0, cB1);
        } else {
            if (nchA == nch) ACC8(vaA, aA0, aA1);
            if (nchB == nch) ACC8(vaB, aB0, aB1);
        }

        // rare tails: padded degree > 64
        if (wA > 64){
            int ee = eA + 64, rem = wA - 64;
            while (rem > 0){
                int win2 = rem < 64 ? rem : 64;
                int iv = csr_src[ee + lane];
                int nc2 = win2 >> 3;
                for (int c = 0; c < nc2; c++){
                    u32 vx[8];
                    GATHER8(vx, iv, c);
                    ACC8(vx, aA0, aA1);
                }
                ee += win2; rem -= win2;
            }
        }
        if (wB > 64){
            int ee = eB + 64, rem = wB - 64;
            while (rem > 0){
                int win2 = rem < 64 ? rem : 64;
                int iv = csr_src[ee + lane];
                int nc2 = win2 >> 3;
                for (int c = 0; c < nc2; c++){
                    u32 vx[8];
                    GATHER8(vx, iv, c);
                    ACC8(vx, aB0, aB1);
                }
                ee += win2; rem -= win2;
            }
        }

        if (nA < NN){
            float di = dinv[nA];
            float x0 = (aA0 + cA0) * di + b0;
            float x1 = (aA1 + cA1) * di + b1;
            u32 o = ((u32)f2b(x1) << 16) | (u32)f2b(x0);
            *reinterpret_cast<u32*>(agg + (size_t)nA * HD + f0) = o;
            s0 += x0; s1 += x1; q0 += x0 * x0; q1 += x1 * x1;
        }
        if (nB < NN){
            float di = dinv[nB];
            float x0 = (aB0 + cB0) * di + b0;
            float x1 = (aB1 + cB1) * di + b1;
            u32 o = ((u32)f2b(x1) << 16) | (u32)f2b(x0);
            *reinterpret_cast<u32*>(agg + (size_t)nB * HD + f0) = o;
            s0 += x0; s1 += x1; q0 += x0 * x0; q1 += x1 * x1;
        }

        ivA = ivA_n; ivB = ivB_n;
    }

    redS[wv][f0] = s0; redS[wv][f0 + 1] = s1;
    redQ[wv][f0] = q0; redQ[wv][f0 + 1] = q1;
    __syncthreads();
    if (tid < HD){
        float ts = redS[0][tid] + redS[1][tid] + redS[2][tid] + redS[3][tid];
        float tq = redQ[0][tid] + redQ[1][tid] + redQ[2][tid] + redQ[3][tid];
        atomicAdd(&sums[tid], ts);
        atomicAdd(&sums[HD + tid], tq);
    }
}

__global__ void k_bnprep(const float* __restrict__ sums, const float* __restrict__ gamma,
                         const float* __restrict__ beta, float* __restrict__ bn){
    int f = threadIdx.x;
    if (f >= HD) return;
    float mu = sums[f] / (float)NN;
    float var = sums[HD + f] / (float)NN - mu * mu;
    float inv = rsqrtf(var + 1e-5f);
    float a = gamma[f] * inv;
    bn[f] = a;
    bn[HD + f] = beta[f] - mu * a;
}

// ---------------- fused BN-apply + head: hA = BN(agg); out += hA @ W_out[row0:row0+128] ----------------
__launch_bounds__(256)
__global__ void k_bnhead(const u16* __restrict__ agg, const float* __restrict__ bn,
                         const float* __restrict__ wout, float* __restrict__ out,
                         u16* __restrict__ hA, int row0){
    __shared__ float wl[HD * NC]; // 20KB
    __shared__ float A[HD];
    __shared__ float C[HD];
    int tid = threadIdx.x;
    for (int i = tid; i < HD * NC; i += 256) wl[i] = wout[row0 * NC + i];
    if (tid < HD){ A[tid] = bn[tid]; C[tid] = bn[HD + tid]; }
    __syncthreads();
    int n = blockIdx.x * 256 + tid;
    if (n >= NN) return;
    float* orw = out + (size_t)n * NC;
    f32x4 acc[10];
    #pragma unroll
    for (int q = 0; q < 10; q++) acc[q] = reinterpret_cast<const f32x4*>(orw)[q];
    #pragma unroll
    for (int k8 = 0; k8 < HD / 8; k8++){
        uint4 v = reinterpret_cast<const uint4*>(agg + (size_t)n * HD)[k8];
        const u16* pv = (const u16*)&v;
        uint4 ov;
        u16* po = (u16*)&ov;
        #pragma unroll
        for (int t = 0; t < 8; t++){
            int f = k8 * 8 + t;
            float xv = b2f(pv[t]) * A[f] + C[f];
            po[t] = f2b(xv);
            const f32x4* wr = reinterpret_cast<const f32x4*>(&wl[f * NC]);
            #pragma unroll
            for (int q = 0; q < 10; q++) acc[q] += xv * wr[q];
        }
        reinterpret_cast<uint4*>(hA + (size_t)n * HD)[k8] = ov;
    }
    #pragma unroll
    for (int q = 0; q < 10; q++) reinterpret_cast<f32x4*>(orw)[q] = acc[q];
}

// ---------------- launch ----------------
extern "C" void kernel_launch(void* const* d_in, const int* in_sizes, int n_in,
                              void* d_out, int out_size, void* d_ws, size_t ws_size,
                              hipStream_t stream){
    const float* x      = (const float*)d_in[0];
    const float* Ws     = (const float*)d_in[1];
    const float* bs     = (const float*)d_in[2];
    const float* gammas = (const float*)d_in[3];
    const float* betas  = (const float*)d_in[4];
    const float* W_out  = (const float*)d_in[5];
    const float* b_out  = (const float*)d_in[6];
    const int*   ei     = (const int*)d_in[7];
    const int* src = ei;
    const int* dst = ei + NE;
    float* out = (float*)d_out;

    char* ws = (char*)d_ws;
    size_t off = 0;
    auto alloc = [&](size_t bytes) -> char* {
        char* p = ws + off;
        off += (bytes + 255) & ~(size_t)255;
        return p;
    };
    u16*   hA       = (u16*)alloc((size_t)NN * HD * 2);
    u16*   hw       = (u16*)alloc((size_t)(NN + 1) * HD * 2);  // +1 zero row for CSR padding
    u16*   aggb     = (u16*)alloc((size_t)NN * HD * 2);        // aliased: bucket buffer pre-loop
    u16*   wt       = (u16*)alloc((size_t)NL * HD * HD * 2);
    float* dinv     = (float*)alloc((size_t)NN * 4);
    int*   offs     = (int*)alloc((size_t)(NBK * NPB) * 4);
    int*   oend     = (int*)alloc((size_t)(NBK * NPB) * 4);
    int*   gcur     = (int*)alloc((size_t)NBK * 4);
    int*   csr_src  = (int*)alloc(((size_t)NBK * PCAP + 256) * 4);
    float* stats    = (float*)alloc((size_t)NL * 2 * HD * 4);
    float* bn       = (float*)alloc((size_t)2 * HD * 4);

    uint2* bb = (uint2*)aggb; // 196*9216*8 = 14.45 MB <= 25.6 MB; dead before layer loop

    hipMemsetAsync(gcur, 0, (size_t)NBK * 4, stream);
    hipMemsetAsync(stats, 0, (size_t)NL * 2 * HD * 4, stream);
    hipMemsetAsync(hw + (size_t)NN * HD, 0, HD * 2, stream);   // zero row NN

    k_conv_w<<<(NL * HD * HD + 255) / 256, 256, 0, stream>>>(Ws, wt);
    k_bin<<<NBINBLK, 256, 0, stream>>>(src, dst, gcur, bb);
    k_csr<<<NBK, 512, 0, stream>>>(gcur, bb, csr_src, offs, oend, dinv);

    k_convhead<<<(NN + 255) / 256, 256, 0, stream>>>(x, W_out, b_out, out, hA);

    for (int l = 0; l < NL; l++){
        k_gemm<<<(NN + 63) / 64, 256, 0, stream>>>(hA, wt + (size_t)l * HD * HD, dinv, hw);
        k_agg<<<(NN + 63) / 64, 256, 0, stream>>>(hw, offs, oend, csr_src, dinv,
                                                  bs + (size_t)l * HD, aggb,
                                                  stats + (size_t)l * 2 * HD);
        k_bnprep<<<1, 128, 0, stream>>>(stats + (size_t)l * 2 * HD,
                                        gammas + (size_t)l * HD, betas + (size_t)l * HD, bn);
        k_bnhead<<<(NN + 255) / 256, 256, 0, stream>>>(aggb, bn, W_out, out, hA,
                                                       HD + l * HD);
    }
}